// Round 2
// baseline (281.652 us; speedup 1.0000x reference)
//
#include <hip/hip_runtime.h>

// SplineCNN on MI355X.
// Sparse edge extraction (adj ~6% dense, basis shared across layers);
// per-layer: split-bf16 MFMA GEMM [B*N,3K]x[3K,640] -> sparse aggregate
// (+root+bias+relu, emits next layer's split-bf16 input).
// Split-bf16: v = hi + lo (bf16 each); A slabs [hi|lo|hi], W slabs [hi;hi;lo]
// -> C = Ahi*Whi + Alo*Whi + Ahi*Wlo (drop lo*lo, ~5e-4 abs err).
// GEMM epilogue emits PAIR-PACKED fp16 taps: hwp[m][kx(3)][py(2)][f(64)] as
// fp16x2 dwords, py-pair = taps (kx,py),(kx,py+1); middle ky=1 duplicated.
// An edge's 4 taps (kx0..+1)x(ky0..+1) = 2 dword loads (base, base+512B)
// -> half the scattered-load instructions of the per-tap layout (the measured
// bottleneck: latency/issue-bound, not bytes). Root slab -> fp32 [M,64].
// Aggregate: XCD-swizzled grid (L2-resident per-XCD slice ~3.7MB), LDS-staged
// edge lists padded to x8, manual 2-deep A/B register pipeline (loads for
// group g+1 in flight while FMA-ing group g).
// Layer-2 aggregate fuses global max-pool via uint-bitcast atomicMax (relu >= 0).

#define B_   32
#define N_   512
#define F_   64
#define CAP  128          // max neighbors per node (mean ~31, 128 is >>6 sigma)
#define NCOL 640          // 9*F (spline kernels) + F (root)
#define TCOL 576          // 9*F tap columns

typedef short bf16x8 __attribute__((ext_vector_type(8)));
typedef float f32x4  __attribute__((ext_vector_type(4)));
typedef _Float16 f16x2 __attribute__((ext_vector_type(2)));

__device__ __forceinline__ unsigned short to_bf16_rne(float v) {
  unsigned u = __float_as_uint(v);
  unsigned r = u + 0x7fffu + ((u >> 16) & 1u);
  return (unsigned short)(r >> 16);
}
__device__ __forceinline__ float bf16_to_f(unsigned short h) {
  return __uint_as_float(((unsigned)h) << 16);
}

// ---------------- preprocess: edge lists + factored spline basis ----------------
// edge record: float4 { bitcast(idx0), fx, fy, 1.0 } where
// idx0 = m*384 + kx0*128 + ky0*64 (dword index into hwp, excl. feature f).
// w=1 marks valid; zero records give all-zero tap weights and idx0=0 (safe).
__global__ __launch_bounds__(512) void preprocess_kernel(
    const float* __restrict__ adj, const float* __restrict__ coord,
    float4* __restrict__ edge, int* __restrict__ cnt_out,
    float* __restrict__ deginv_out) {
  int row = blockIdx.x;          // b*N + n
  int b = row >> 9;
  int tid = threadIdx.x;         // == m
  int lane = tid & 63, wave = tid >> 6;
  __shared__ int wcnt[8];
  float a = adj[(size_t)row * N_ + tid];
  bool flag = (a != 0.0f);
  unsigned long long ball = __ballot(flag);
  if (lane == 0) wcnt[wave] = __popcll(ball);
  __syncthreads();
  int woff = 0, total = 0;
  #pragma unroll
  for (int i = 0; i < 8; ++i) { int c = wcnt[i]; if (i < wave) woff += c; total += c; }
  if (flag) {
    int pos = woff + __popcll(ball & ((1ULL << lane) - 1));
    if (pos < CAP) {
      int m = tid;
      float cxn = coord[(size_t)row * 2 + 0];
      float cyn = coord[(size_t)row * 2 + 1];
      float cxm = coord[(size_t)(b * N_ + m) * 2 + 0];
      float cym = coord[(size_t)(b * N_ + m) * 2 + 1];
      float vx = (cxm - cxn + 1.0f) * 0.5f * 2.0f;
      float vy = (cym - cyn + 1.0f) * 0.5f * 2.0f;
      float i0x = fminf(fmaxf(floorf(vx), 0.0f), 1.0f);
      float i0y = fminf(fmaxf(floorf(vy), 0.0f), 1.0f);
      float fx = vx - i0x, fy = vy - i0y;
      int idx0 = m * 384 + (int)i0x * 128 + (int)i0y * 64;
      edge[(size_t)row * CAP + pos] =
          make_float4(__int_as_float(idx0), fx, fy, 1.0f);
    }
  }
  if (tid == 0) {
    cnt_out[row] = total > CAP ? CAP : total;
    deginv_out[row] = 1.0f / (float)(total > 0 ? total : 1);
  }
}

// ---------------- convert x (fp32 [M,128]) -> split-bf16 A [M, 384] ----------------
__global__ void convx_kernel(const float* __restrict__ x, unsigned short* __restrict__ a) {
  int idx = blockIdx.x * blockDim.x + threadIdx.x;
  if (idx >= B_ * N_ * 128) return;
  int row = idx >> 7, k = idx & 127;
  float v = x[idx];
  unsigned short hi = to_bf16_rne(v);
  unsigned short lo = to_bf16_rne(v - bf16_to_f(hi));
  size_t base = (size_t)row * 384;
  a[base + k] = hi;
  a[base + 128 + k] = lo;
  a[base + 256 + k] = hi;
}

// ---- pack w (9 slices)+root -> W^T split-bf16 [640 n][3*cin k'] (slabs hi,hi,lo) ----
__global__ void packw_kernel(const float* __restrict__ w, const float* __restrict__ root,
                             int cin, unsigned short* __restrict__ wt) {
  int idx = blockIdx.x * blockDim.x + threadIdx.x;
  int total = NCOL * cin;
  if (idx >= total) return;
  int n = idx / cin, k = idx - n * cin;
  int kk = n >> 6, f = n & 63;
  float v = (kk < 9) ? w[((size_t)kk * cin + k) * F_ + f]
                     : root[(size_t)k * F_ + f];
  unsigned short hi = to_bf16_rne(v);
  unsigned short lo = to_bf16_rne(v - bf16_to_f(hi));
  size_t base = (size_t)n * (3 * cin);
  wt[base + k] = hi;
  wt[base + cin + k] = hi;
  wt[base + 2 * cin + k] = lo;
}

// ---------------- split-bf16 MFMA GEMM: [M,640] = A[M,KP] * Wt[640,KP]^T ----------------
// 128x128 tile, 256 threads = 4 waves (2x2 of 64x64), 16x16x32 bf16 MFMA, BK=64.
// LDS rows padded +8 bf16 (stride 144B = 9 words -> conflict-free b128 frag reads).
// Epilogue: each 64-col slab is wave-uniform (k = (bn+nw)>>6). Tap slabs k<9 ->
// pair-packed fp16 hwp (ky<=1 -> py=ky slot lo; ky>=1 -> py=ky-1 slot hi);
// root slab k==9 -> fp32 rootf.
#define BK 64
#define LDK (BK + 8)
__global__ __launch_bounds__(256) void gemm_mfma_kernel(
    const unsigned short* __restrict__ A,   // [M][KP]
    const unsigned short* __restrict__ Wt,  // [640][KP]  (W^T, n-major)
    _Float16* __restrict__ hwp,             // [M][3 kx][2 py][64 f][2] fp16
    float* __restrict__ rootf,              // [M][64] fp32 root slab
    int KP) {
  __shared__ unsigned short As[128 * LDK];
  __shared__ unsigned short Ws[128 * LDK];
  int bm = blockIdx.x * 128;
  int bn = blockIdx.y * 128;
  int tid = threadIdx.x;
  int wave = tid >> 6, lane = tid & 63;
  int mw = (wave & 1) * 64, nw = (wave >> 1) * 64;
  int lr = lane & 15, quad = lane >> 4;

  f32x4 acc[4][4] = {};
  for (int k0 = 0; k0 < KP; k0 += BK) {
    #pragma unroll
    for (int i = 0; i < 4; ++i) {
      int c = tid + i * 256;            // 0..1023 chunks of 16B
      int row = c >> 3, ck = (c & 7) * 8;
      *(float4*)&As[row * LDK + ck] =
          *(const float4*)&A[(size_t)(bm + row) * KP + k0 + ck];
      *(float4*)&Ws[row * LDK + ck] =
          *(const float4*)&Wt[(size_t)(bn + row) * KP + k0 + ck];
    }
    __syncthreads();
    #pragma unroll
    for (int kk = 0; kk < BK; kk += 32) {
      bf16x8 af[4], bf[4];
      #pragma unroll
      for (int i = 0; i < 4; ++i)
        af[i] = *(const bf16x8*)&As[(mw + 16 * i + lr) * LDK + kk + quad * 8];
      #pragma unroll
      for (int j = 0; j < 4; ++j)
        bf[j] = *(const bf16x8*)&Ws[(nw + 16 * j + lr) * LDK + kk + quad * 8];
      #pragma unroll
      for (int i = 0; i < 4; ++i)
        #pragma unroll
        for (int j = 0; j < 4; ++j)
          acc[i][j] = __builtin_amdgcn_mfma_f32_16x16x32_bf16(af[i], bf[j], acc[i][j], 0, 0, 0);
    }
    __syncthreads();
  }
  // epilogue: C/D layout col=lane&15, row=quad*4+reg (m89-verified).
  // n = bn + nw + 16j + lr spans exactly one 64-col slab per wave.
  int kslab = (bn + nw) >> 6;   // 0..9, wave-uniform
  if (kslab < 9) {
    int kx = kslab / 3;
    int ky = kslab - 3 * kx;
    #pragma unroll
    for (int i = 0; i < 4; ++i)
      #pragma unroll
      for (int j = 0; j < 4; ++j)
        #pragma unroll
        for (int r = 0; r < 4; ++r) {
          int m = bm + mw + 16 * i + quad * 4 + r;
          int fcol = 16 * j + lr;
          _Float16 h = (_Float16)acc[i][j][r];
          // ushort index = 2*(m*384 + kx*128 + py*64 + f) + hslot
          size_t base = ((size_t)m * 384 + kx * 128 + fcol) * 2;
          if (ky <= 1) hwp[base + (size_t)ky * 128] = h;
          if (ky >= 1) hwp[base + (size_t)(ky - 1) * 128 + 1] = h;
        }
  } else {
    #pragma unroll
    for (int i = 0; i < 4; ++i)
      #pragma unroll
      for (int j = 0; j < 4; ++j)
        #pragma unroll
        for (int r = 0; r < 4; ++r) {
          int m = bm + mw + 16 * i + quad * 4 + r;
          rootf[(size_t)m * F_ + 16 * j + lr] = acc[i][j][r];
        }
  }
}

// ---------------- sparse aggregate ----------------
// 256 threads = 4 waves, one row per wave. XCD-swizzled (blockIdx&7 = XCD).
// Edge lists staged to LDS, padded to x8 (+8 zero records for overshoot).
// Per edge: 2 dword gathers from pair-packed fp16 hwp (base, base+512B);
// manual 2-deep A/B register pipeline keeps next group's 8 loads in flight
// while converting+FMA-ing the current group.
// Emits next layer's split-bf16 A (aout: [row][192] = hi|lo|hi) and/or gmax.
__global__ __launch_bounds__(256) void aggregate_kernel(
    const unsigned int* __restrict__ hwp,   // dword view of pair-packed taps
    const float* __restrict__ rootf,
    const float4* __restrict__ edge,
    const int* __restrict__ cnt, const float* __restrict__ deginv,
    const float* __restrict__ bias,
    unsigned short* __restrict__ aout,
    unsigned int* __restrict__ gmax) {
  __shared__ float4 esh[4][CAP + 8];
  int wave = threadIdx.x >> 6;
  int lane = threadIdx.x & 63;
  int f = lane;
  int xcd = blockIdx.x & 7;
  int j = blockIdx.x >> 3;
  int b = xcd * 4 + (j >> 7);
  int row = b * N_ + ((j & 127) << 2) + wave;
  int c = cnt[row];
  int cpad = (c + 7) & ~7;
  size_t ebase = (size_t)row * CAP;
  for (int i = lane; i < cpad + 8; i += 64)
    esh[wave][i] = (i < c) ? edge[ebase + i] : make_float4(0.f, 0.f, 0.f, 0.f);
  __syncthreads();

  float di = deginv[row];
  const unsigned int* hb = hwp + (size_t)b * N_ * 384;
  float acc0 = 0.f, acc1 = 0.f, acc2 = 0.f, acc3 = 0.f;

#define LOADG(P, e) { \
    int i0 = __float_as_int(esh[wave][(e) + 0].x) + f; \
    int i1 = __float_as_int(esh[wave][(e) + 1].x) + f; \
    int i2 = __float_as_int(esh[wave][(e) + 2].x) + f; \
    int i3 = __float_as_int(esh[wave][(e) + 3].x) + f; \
    P##0 = hb[i0]; P##1 = hb[i0 + 128]; \
    P##2 = hb[i1]; P##3 = hb[i1 + 128]; \
    P##4 = hb[i2]; P##5 = hb[i2 + 128]; \
    P##6 = hb[i3]; P##7 = hb[i3 + 128]; }

#define CONS1(ulo, uhi, er, acc) { \
    float bx1 = (er).y, by1 = (er).z, vv = (er).w; \
    float bx0 = vv - bx1, by0 = vv - by1; \
    f16x2 p0 = __builtin_bit_cast(f16x2, ulo); \
    f16x2 p1 = __builtin_bit_cast(f16x2, uhi); \
    acc += (bx0 * by0) * (float)p0[0] + (bx0 * by1) * (float)p0[1] \
         + (bx1 * by0) * (float)p1[0] + (bx1 * by1) * (float)p1[1]; }

#define CONSG(P, e) { \
    float4 e0r = esh[wave][(e) + 0]; CONS1(P##0, P##1, e0r, acc0); \
    float4 e1r = esh[wave][(e) + 1]; CONS1(P##2, P##3, e1r, acc1); \
    float4 e2r = esh[wave][(e) + 2]; CONS1(P##4, P##5, e2r, acc2); \
    float4 e3r = esh[wave][(e) + 3]; CONS1(P##6, P##7, e3r, acc3); }

  unsigned A0 = 0, A1 = 0, A2 = 0, A3 = 0, A4 = 0, A5 = 0, A6 = 0, A7 = 0;
  unsigned B0, B1, B2, B3, B4, B5, B6, B7;
  if (cpad > 0) {
    LOADG(A, 0);
    for (int e0 = 0; e0 < cpad; e0 += 8) {
      LOADG(B, e0 + 4);          // in flight behind A's consume
      CONSG(A, e0);
      LOADG(A, e0 + 8);          // overshoot reads zero-pad records (safe)
      CONSG(B, e0 + 4);
    }
  }
#undef LOADG
#undef CONS1
#undef CONSG

  float rootv = rootf[(size_t)row * F_ + f];
  float val = fmaxf(((acc0 + acc1) + (acc2 + acc3)) * di + rootv + bias[f], 0.0f);
  if (aout) {
    unsigned short hi = to_bf16_rne(val);
    unsigned short lo = to_bf16_rne(val - bf16_to_f(hi));
    size_t base = (size_t)row * 192;
    aout[base + f] = hi;
    aout[base + 64 + f] = lo;
    aout[base + 128 + f] = hi;
  }
  if (gmax) {
    // relu output >= 0 -> IEEE bits monotone under unsigned compare
    atomicMax(&gmax[b * F_ + f], __float_as_uint(val));
  }
}

// ---------------- zero the pooled-max buffer ----------------
__global__ void zerog_kernel(unsigned int* __restrict__ g) {
  int i = blockIdx.x * blockDim.x + threadIdx.x;
  if (i < B_ * F_) g[i] = 0u;
}

// ---------------- FC from pooled features ----------------
__global__ __launch_bounds__(64) void fc_kernel(
    const float* __restrict__ g, const float* __restrict__ fcw,
    const float* __restrict__ fcb, float* __restrict__ out) {
  int b = blockIdx.x;
  int f = threadIdx.x;
  __shared__ float gs[64];
  gs[f] = g[b * F_ + f];
  __syncthreads();
  if (f < 10) {
    float s = fcb[f];
    #pragma unroll
    for (int c = 0; c < 64; ++c) s += gs[c] * fcw[c * 10 + f];
    out[b * 10 + f] = s;
  }
}

extern "C" void kernel_launch(void* const* d_in, const int* in_sizes, int n_in,
                              void* d_out, int out_size, void* d_ws, size_t ws_size,
                              hipStream_t stream) {
  const float* x     = (const float*)d_in[0];
  const float* coord = (const float*)d_in[1];
  const float* adj   = (const float*)d_in[2];
  const float* w0    = (const float*)d_in[3];
  const float* root0 = (const float*)d_in[4];
  const float* b0    = (const float*)d_in[5];
  const float* w1    = (const float*)d_in[6];
  const float* root1 = (const float*)d_in[7];
  const float* b1    = (const float*)d_in[8];
  const float* w2    = (const float*)d_in[9];
  const float* root2 = (const float*)d_in[10];
  const float* b2    = (const float*)d_in[11];
  const float* fcw   = (const float*)d_in[12];
  const float* fcb   = (const float*)d_in[13];
  float* out = (float*)d_out;

  char* ws = (char*)d_ws;
  size_t off = 0;
  auto alloc = [&](size_t bytes) {
    void* p = ws + off;
    off = (off + bytes + 255) & ~(size_t)255;
    return p;
  };
  const int R = B_ * N_;  // 16384
  float4* edge    = (float4*)alloc((size_t)R * CAP * 16);
  int*    cnt     = (int*)   alloc((size_t)R * 4);
  float*  deginv  = (float*) alloc((size_t)R * 4);
  unsigned short* abf0 = (unsigned short*)alloc((size_t)R * 384 * 2);
  unsigned short* abfN = (unsigned short*)alloc((size_t)R * 192 * 2);
  unsigned short* wt   = (unsigned short*)alloc((size_t)NCOL * 384 * 2);
  _Float16* hwp   = (_Float16*)alloc((size_t)R * 384 * 4);  // pair-packed taps
  float*  rootf   = (float*) alloc((size_t)R * F_ * 4);
  unsigned int* gmax = (unsigned int*)alloc((size_t)B_ * F_ * 4);

  preprocess_kernel<<<R, 512, 0, stream>>>(adj, coord, edge, cnt, deginv);
  zerog_kernel<<<(B_ * F_ + 255) / 256, 256, 0, stream>>>(gmax);
  convx_kernel<<<(R * 128 + 255) / 256, 256, 0, stream>>>(x, abf0);

  // layer 0 (Cin=128, KP=384)
  packw_kernel<<<(NCOL * 128 + 255) / 256, 256, 0, stream>>>(w0, root0, 128, wt);
  gemm_mfma_kernel<<<dim3(R / 128, NCOL / 128), 256, 0, stream>>>(abf0, wt, hwp, rootf, 384);
  aggregate_kernel<<<R / 4, 256, 0, stream>>>((const unsigned int*)hwp, rootf, edge, cnt, deginv, b0, abfN, nullptr);

  // layer 1 (Cin=64, KP=192)
  packw_kernel<<<(NCOL * 64 + 255) / 256, 256, 0, stream>>>(w1, root1, 64, wt);
  gemm_mfma_kernel<<<dim3(R / 128, NCOL / 128), 256, 0, stream>>>(abfN, wt, hwp, rootf, 192);
  aggregate_kernel<<<R / 4, 256, 0, stream>>>((const unsigned int*)hwp, rootf, edge, cnt, deginv, b1, abfN, nullptr);

  // layer 2 (Cin=64, KP=192) — fused max-pool
  packw_kernel<<<(NCOL * 64 + 255) / 256, 256, 0, stream>>>(w2, root2, 64, wt);
  gemm_mfma_kernel<<<dim3(R / 128, NCOL / 128), 256, 0, stream>>>(abfN, wt, hwp, rootf, 192);
  aggregate_kernel<<<R / 4, 256, 0, stream>>>((const unsigned int*)hwp, rootf, edge, cnt, deginv, b2, nullptr, gmax);

  fc_kernel<<<B_, 64, 0, stream>>>((const float*)gmax, fcw, fcb, out);
}